// Round 6
// baseline (233.883 us; speedup 1.0000x reference)
//
#include <hip/hip_runtime.h>

#define DM 256
#define NMAX 64

// ws layout (floats):
//   baseDisk [64][256]  off 0      : disk_b + disk_type + fourier(i) @ disk_W
//   ridproj  [3][256]   off 16384  : rod_id_embed[s] @ disk_W[21..28]
//   baseRod  [3][256]   off 17152  : rod_b + rod_type + rod_id(r) @ rod_W
//   rodTop   [65][256]  off 17920  : fourier(idx) @ rod_W[4..19]   (idx 64 = null_fourier)
//   rodBot   [65][256]  off 34560  : fourier(idx) @ rod_W[20..35]
#define OFF_RIDPROJ 16384
#define OFF_BASEROD 17152
#define OFF_RODTOP  17920
#define OFF_RODBOT  34560

typedef float vf4 __attribute__((ext_vector_type(4)));

static __device__ __forceinline__ vf4 ld4(const float* p) {
  return *reinterpret_cast<const vf4*>(p);
}
static __device__ __forceinline__ void st4_nt(float* p, vf4 v) {
  __builtin_nontemporal_store(v, reinterpret_cast<vf4*>(p));
}

__global__ void precomp_kernel(
    const float* __restrict__ rod_id_embed,
    const float* __restrict__ disk_W,
    const float* __restrict__ disk_b,
    const float* __restrict__ rod_W,
    const float* __restrict__ rod_b,
    const float* __restrict__ null_fourier,
    float* __restrict__ ws) {
  const int idx = blockIdx.x;   // 0..64 (64 = null fourier row)
  const int d = threadIdx.x;    // 0..255

  float F[16];
  if (idx < 64) {
#pragma unroll
    for (int k = 0; k < 8; ++k) {
      float omega = powf(10000.0f, -(float)k * 0.125f);
      float a = (float)idx * omega;
      F[2 * k]     = sinf(a);
      F[2 * k + 1] = cosf(a);
    }
  } else {
#pragma unroll
    for (int k = 0; k < 16; ++k) F[k] = null_fourier[k];
  }

  float* baseDisk = ws;
  float* ridproj  = ws + OFF_RIDPROJ;
  float* baseRod  = ws + OFF_BASEROD;
  float* rodTop   = ws + OFF_RODTOP;
  float* rodBot   = ws + OFF_RODBOT;

  float t = 0.f, bo = 0.f;
#pragma unroll
  for (int k = 0; k < 16; ++k) {
    t  += F[k] * rod_W[(4 + k) * DM + d];
    bo += F[k] * rod_W[(20 + k) * DM + d];
  }
  rodTop[idx * DM + d] = t;
  rodBot[idx * DM + d] = bo;

  if (idx < 64) {
    float base = disk_b[d] + disk_W[0 * DM + d];  // disk_type = [1,0]
#pragma unroll
    for (int k = 0; k < 16; ++k) base += F[k] * disk_W[(2 + k) * DM + d];
    baseDisk[(size_t)idx * DM + d] = base;
  }
  if (idx < 3) {
    float rp = 0.f;
    float br = rod_b[d] + rod_W[1 * DM + d];  // rod_type = [0,1]
#pragma unroll
    for (int j = 0; j < 8; ++j) {
      rp += rod_id_embed[idx * 8 + j] * disk_W[(21 + j) * DM + d];
      br += rod_id_embed[idx * 8 + j] * rod_W[(36 + j) * DM + d];
    }
    ridproj[idx * DM + d] = rp;
    baseRod[idx * DM + d] = br;
  }
}

// Persistent: 2048 blocks (4 waves each), block handles 8 consecutive batch
// elements; XCD-chunked bijective swizzle so each XCD writes one contiguous
// ~140MB region. No LDS, no barrier; meta broadcast via readlane.
#define BPB 8   // batch elements per block

__launch_bounds__(256)
__global__ void enc_kernel(
    const int* __restrict__ state,
    const float* __restrict__ disk_W,
    const float* __restrict__ rod_W,
    const float* __restrict__ padding_embedding,
    const float* __restrict__ ws,
    float* __restrict__ out,
    int Btot) {
  const float* baseDisk = ws;
  const float* ridproj  = ws + OFF_RIDPROJ;
  const float* baseRod  = ws + OFF_BASEROD;
  const float* rodTop   = ws + OFF_RODTOP;
  const float* rodBot   = ws + OFF_RODBOT;

  const int tid  = threadIdx.x;
  const int q    = tid >> 6;     // wave 0..3 within the block
  const int lane = tid & 63;     // lane = disk position

  // XCD-chunked bijective swizzle (nwg % 8 == 0 enforced by launcher)
  const int nwg  = gridDim.x;
  const int bid  = blockIdx.x;
  const int wgid = (bid & 7) * (nwg >> 3) + (bid >> 3);

  // ---- per-block hoisted weight rows ----
  const int c0 = lane * 4;  // 4 consecutive floats per lane -> 16B IO
  const vf4 Wdep = ld4(disk_W + 18 * DM + c0);
  const vf4 Wt   = ld4(disk_W + 19 * DM + c0);
  const vf4 Wb   = ld4(disk_W + 20 * DM + c0);
  const vf4 pad  = ld4(padding_embedding + c0);
  const vf4 rp0  = ld4(ridproj + 0 * DM + c0);
  const vf4 rp1  = ld4(ridproj + 1 * DM + c0);
  const vf4 rp2  = ld4(ridproj + 2 * DM + c0);
  const vf4 rW2  = ld4(rod_W + 2 * DM + c0);
  const vf4 rW3  = ld4(rod_W + 3 * DM + c0);
  const vf4 bR   = (q < 3) ? ld4(baseRod + q * DM + c0) : pad;

  for (int bb = 0; bb < BPB; ++bb) {
    const long b = (long)wgid * BPB + bb;
    if (b >= Btot) break;

    // ---- per-batch combinatorics via ballot ----
    const int s = state[b * NMAX + lane];
    const bool valid = (s >= 0);
    const int ss = s <= 0 ? 0 : (s >= 2 ? 2 : s);  // clip(s,0,2)
    const unsigned long long m0 = __ballot(valid && s == 0);
    const unsigned long long m1 = __ballot(valid && s == 1);
    const unsigned long long m2 = __ballot(valid && s == 2);
    const unsigned long long vm = __ballot(valid);
    const unsigned long long mym = (ss == 0) ? m0 : ((ss == 1) ? m1 : m2);
    const int above  = __popcll(mym & ((1ull << lane) - 1ull));
    const int height = __popcll(mym);

    // per-lane disk meta (lane = position i)
    const float depf =
        (valid && height > 1) ? (float)above / (float)(height - 1) : 0.f;
    const int flags = valid ? ((ss + 1) | (above == 0 ? 4 : 0) |
                               (above == height - 1 ? 8 : 0))
                            : 0;

    // per-lane rod meta (meaningful in lanes 0..2 only)
    const unsigned long long mr = (lane == 0) ? m0 : ((lane == 1) ? m1 : m2);
    const int cnt = __popcll(mr);
    const int lengths = __popcll(vm);
    const float lnf = (float)cnt / (float)(lengths > 1 ? lengths : 1);
    const int ti = cnt ? (int)__builtin_ctzll(mr) : 64;
    const int bi = cnt ? 63 - (int)__builtin_clzll(mr) : 64;
    const int rodpack = ti | (bi << 8) | ((cnt == 0) ? 0x10000 : 0);

    float* outB = out + (size_t)b * 67 * DM;

    // ---- rod row (waves 0..2 handle row q) ----
    if (q < 3) {
      const float ln = __uint_as_float(
          __builtin_amdgcn_readlane(__float_as_uint(lnf), q));
      const int rpk = __builtin_amdgcn_readlane(rodpack, q);
      const int rti = rpk & 0xff;
      const int rbi = (rpk >> 8) & 0xff;
      const float em = (float)((rpk >> 16) & 1);
      vf4 v = bR;
      v += ld4(rodTop + (size_t)rti * DM + c0);
      v += ld4(rodBot + (size_t)rbi * DM + c0);
      v += ln * rW2 + em * rW3;
      st4_nt(outB + q * DM + c0, v);
    } else {
      // wave 3 handles row 3 (disk i = 0)
      const int fl = __builtin_amdgcn_readlane(flags, 0);
      const float dep = __uint_as_float(
          __builtin_amdgcn_readlane(__float_as_uint(depf), 0));
      vf4 v;
      if (fl) {
        const vf4 base = ld4(baseDisk + c0);
        const int code = fl & 3;
        const vf4 rp = (code == 1) ? rp0 : ((code == 2) ? rp1 : rp2);
        const float tt = (float)((fl >> 2) & 1);
        const float bb2 = (float)((fl >> 3) & 1);
        v = base + rp + dep * Wdep + tt * Wt + bb2 * Wb;
      } else {
        v = pad;
      }
      st4_nt(outB + 3 * DM + c0, v);
    }

    // ---- disk rows: r = q+4, q+8, ... ; i = r-3 ----
#pragma unroll 4
    for (int r = q + 4; r < 67; r += 4) {
      const int i = r - 3;
      const int fl = __builtin_amdgcn_readlane(flags, i);     // uniform
      const float dep = __uint_as_float(
          __builtin_amdgcn_readlane(__float_as_uint(depf), i));
      vf4 v;
      if (fl) {
        const vf4 base = ld4(baseDisk + (size_t)i * DM + c0);
        const int code = fl & 3;  // 1..3
        const vf4 rp = (code == 1) ? rp0 : ((code == 2) ? rp1 : rp2);
        const float tt = (float)((fl >> 2) & 1);
        const float bb2 = (float)((fl >> 3) & 1);
        v = base + rp + dep * Wdep + tt * Wt + bb2 * Wb;
      } else {
        v = pad;
      }
      st4_nt(outB + (size_t)r * DM + c0, v);
    }
  }
}

extern "C" void kernel_launch(void* const* d_in, const int* in_sizes, int n_in,
                              void* d_out, int out_size, void* d_ws, size_t ws_size,
                              hipStream_t stream) {
  const int*   state             = (const int*)d_in[0];
  const float* rod_id_embed      = (const float*)d_in[1];
  const float* disk_W            = (const float*)d_in[2];
  const float* disk_b            = (const float*)d_in[3];
  const float* rod_W             = (const float*)d_in[4];
  const float* rod_b             = (const float*)d_in[5];
  const float* null_fourier      = (const float*)d_in[6];
  const float* padding_embedding = (const float*)d_in[7];
  float* ws  = (float*)d_ws;
  float* out = (float*)d_out;

  const int B = in_sizes[0] / NMAX;

  // grid: ceil(B / BPB), rounded up to a multiple of 8 so the XCD swizzle
  // is bijective (extra blocks exit via the b >= Btot check).
  int nwg = (B + BPB - 1) / BPB;
  nwg = (nwg + 7) & ~7;

  hipLaunchKernelGGL(precomp_kernel, dim3(65), dim3(256), 0, stream,
                     rod_id_embed, disk_W, disk_b, rod_W, rod_b, null_fourier, ws);
  hipLaunchKernelGGL(enc_kernel, dim3(nwg), dim3(256), 0, stream,
                     state, disk_W, rod_W, padding_embedding, ws, out, B);
}

// Round 7
// 220.828 us; speedup vs baseline: 1.0591x; 1.0591x over previous
//
#include <hip/hip_runtime.h>

#define DM 256
#define NMAX 64

// ws layout (floats):
//   baseDisk [64][256]  off 0      : disk_b + disk_type + fourier(i) @ disk_W
//   ridproj  [3][256]   off 16384  : rod_id_embed[s] @ disk_W[21..28]
//   baseRod  [3][256]   off 17152  : rod_b + rod_type + rod_id(r) @ rod_W
//   rodTop   [65][256]  off 17920  : fourier(idx) @ rod_W[4..19]   (idx 64 = null_fourier)
//   rodBot   [65][256]  off 34560  : fourier(idx) @ rod_W[20..35]
#define OFF_RIDPROJ 16384
#define OFF_BASEROD 17152
#define OFF_RODTOP  17920
#define OFF_RODBOT  34560

typedef float vf4 __attribute__((ext_vector_type(4)));

static __device__ __forceinline__ vf4 ld4(const float* p) {
  return *reinterpret_cast<const vf4*>(p);
}
static __device__ __forceinline__ void st4_nt(float* p, vf4 v) {
  __builtin_nontemporal_store(v, reinterpret_cast<vf4*>(p));
}

// omega_k = 10000^(-k/8), hard-coded (removes runtime powf)
__constant__ float OMEGA[8] = {
    1.0f, 0.31622776601683794f, 0.1f, 0.031622776601683791f,
    0.01f, 0.0031622776601683794f, 0.001f, 0.00031622776601683794f};

__global__ void precomp_kernel(
    const float* __restrict__ rod_id_embed,
    const float* __restrict__ disk_W,
    const float* __restrict__ disk_b,
    const float* __restrict__ rod_W,
    const float* __restrict__ rod_b,
    const float* __restrict__ null_fourier,
    float* __restrict__ ws) {
  const int idx = blockIdx.x;   // 0..64 (64 = null fourier row)
  const int d = threadIdx.x;    // 0..255

  float F[16];
  if (idx < 64) {
#pragma unroll
    for (int k = 0; k < 8; ++k) {
      float a = (float)idx * OMEGA[k];
      F[2 * k]     = sinf(a);
      F[2 * k + 1] = cosf(a);
    }
  } else {
#pragma unroll
    for (int k = 0; k < 16; ++k) F[k] = null_fourier[k];
  }

  float* baseDisk = ws;
  float* ridproj  = ws + OFF_RIDPROJ;
  float* baseRod  = ws + OFF_BASEROD;
  float* rodTop   = ws + OFF_RODTOP;
  float* rodBot   = ws + OFF_RODBOT;

  float t = 0.f, bo = 0.f;
#pragma unroll
  for (int k = 0; k < 16; ++k) {
    t  += F[k] * rod_W[(4 + k) * DM + d];
    bo += F[k] * rod_W[(20 + k) * DM + d];
  }
  rodTop[idx * DM + d] = t;
  rodBot[idx * DM + d] = bo;

  if (idx < 64) {
    float base = disk_b[d] + disk_W[0 * DM + d];  // disk_type = [1,0]
#pragma unroll
    for (int k = 0; k < 16; ++k) base += F[k] * disk_W[(2 + k) * DM + d];
    baseDisk[(size_t)idx * DM + d] = base;
  }
  if (idx < 3) {
    float rp = 0.f;
    float br = rod_b[d] + rod_W[1 * DM + d];  // rod_type = [0,1]
#pragma unroll
    for (int j = 0; j < 8; ++j) {
      rp += rod_id_embed[idx * 8 + j] * disk_W[(21 + j) * DM + d];
      br += rod_id_embed[idx * 8 + j] * rod_W[(36 + j) * DM + d];
    }
    ridproj[idx * DM + d] = rp;
    baseRod[idx * DM + d] = br;
  }
}

// One block (4 waves) per batch element. Wave q owns disk indices
// i = q, q+4, ..., q+60 (16 each); waves 0..2 additionally own rod row q.
// All 16 base rows are prefetched into registers BEFORE the meta compute,
// so every store's operands are register-resident at store time.
__launch_bounds__(256)
__global__ void enc_kernel(
    const int* __restrict__ state,
    const float* __restrict__ disk_W,
    const float* __restrict__ rod_W,
    const float* __restrict__ padding_embedding,
    const float* __restrict__ ws,
    float* __restrict__ out) {
  const float* baseDisk = ws;
  const float* ridproj  = ws + OFF_RIDPROJ;
  const float* baseRod  = ws + OFF_BASEROD;
  const float* rodTop   = ws + OFF_RODTOP;
  const float* rodBot   = ws + OFF_RODBOT;

  const int tid  = threadIdx.x;
  const int q    = tid >> 6;     // wave 0..3
  const int lane = tid & 63;     // lane = disk position
  const long b   = blockIdx.x;
  const int c0   = lane * 4;

  // ---- prefetch: 16 independent base-row loads issued first ----
  vf4 base[16];
#pragma unroll
  for (int k = 0; k < 16; ++k)
    base[k] = ld4(baseDisk + (size_t)(q + 4 * k) * DM + c0);

  // ---- per-batch combinatorics via ballot (overlaps the loads) ----
  const int s = state[b * NMAX + lane];
  const bool valid = (s >= 0);
  const int ss = s <= 0 ? 0 : (s >= 2 ? 2 : s);  // clip(s,0,2)
  const unsigned long long m0 = __ballot(valid && s == 0);
  const unsigned long long m1 = __ballot(valid && s == 1);
  const unsigned long long m2 = __ballot(valid && s == 2);
  const unsigned long long vm = __ballot(valid);
  const unsigned long long mym = (ss == 0) ? m0 : ((ss == 1) ? m1 : m2);
  const int above  = __popcll(mym & ((1ull << lane) - 1ull));
  const int height = __popcll(mym);

  const float depf =
      (valid && height > 1) ? (float)above / (float)(height - 1) : 0.f;
  const int flags = valid ? ((ss + 1) | (above == 0 ? 4 : 0) |
                             (above == height - 1 ? 8 : 0))
                          : 0;

  const unsigned long long mr = (lane == 0) ? m0 : ((lane == 1) ? m1 : m2);
  const int cnt = __popcll(mr);
  const int lengths = __popcll(vm);
  const float lnf = (float)cnt / (float)(lengths > 1 ? lengths : 1);
  const int ti = cnt ? (int)__builtin_ctzll(mr) : 64;
  const int bi = cnt ? 63 - (int)__builtin_clzll(mr) : 64;
  const int rodpack = ti | (bi << 8) | ((cnt == 0) ? 0x10000 : 0);

  const vf4 Wdep = ld4(disk_W + 18 * DM + c0);
  const vf4 Wt   = ld4(disk_W + 19 * DM + c0);
  const vf4 Wb   = ld4(disk_W + 20 * DM + c0);
  const vf4 pad  = ld4(padding_embedding + c0);
  const vf4 rp0  = ld4(ridproj + 0 * DM + c0);
  const vf4 rp1  = ld4(ridproj + 1 * DM + c0);
  const vf4 rp2  = ld4(ridproj + 2 * DM + c0);

  float* outB = out + (size_t)b * 67 * DM;

  // ---- rod row (waves 0..2) ----
  if (q < 3) {
    const vf4 rW2 = ld4(rod_W + 2 * DM + c0);
    const vf4 rW3 = ld4(rod_W + 3 * DM + c0);
    const float ln = __uint_as_float(
        __builtin_amdgcn_readlane(__float_as_uint(lnf), q));
    const int rpk = __builtin_amdgcn_readlane(rodpack, q);
    const int rti = rpk & 0xff;
    const int rbi = (rpk >> 8) & 0xff;
    const float em = (float)((rpk >> 16) & 1);
    vf4 v = ld4(baseRod + q * DM + c0);
    v += ld4(rodTop + (size_t)rti * DM + c0);
    v += ld4(rodBot + (size_t)rbi * DM + c0);
    v += ln * rW2 + em * rW3;
    st4_nt(outB + q * DM + c0, v);
  }

  // ---- disk rows from registers: i = q + 4k, output row = i + 3 ----
#pragma unroll
  for (int k = 0; k < 16; ++k) {
    const int i = q + 4 * k;
    const int fl = __builtin_amdgcn_readlane(flags, i);     // uniform
    const float dep = __uint_as_float(
        __builtin_amdgcn_readlane(__float_as_uint(depf), i));
    vf4 v;
    if (fl) {
      const int code = fl & 3;  // 1..3
      const vf4 rp = (code == 1) ? rp0 : ((code == 2) ? rp1 : rp2);
      const float tt = (float)((fl >> 2) & 1);
      const float bb = (float)((fl >> 3) & 1);
      v = base[k] + rp + dep * Wdep + tt * Wt + bb * Wb;
    } else {
      v = pad;
    }
    st4_nt(outB + (size_t)(3 + i) * DM + c0, v);
  }
}

extern "C" void kernel_launch(void* const* d_in, const int* in_sizes, int n_in,
                              void* d_out, int out_size, void* d_ws, size_t ws_size,
                              hipStream_t stream) {
  const int*   state             = (const int*)d_in[0];
  const float* rod_id_embed      = (const float*)d_in[1];
  const float* disk_W            = (const float*)d_in[2];
  const float* disk_b            = (const float*)d_in[3];
  const float* rod_W             = (const float*)d_in[4];
  const float* rod_b             = (const float*)d_in[5];
  const float* null_fourier      = (const float*)d_in[6];
  const float* padding_embedding = (const float*)d_in[7];
  float* ws  = (float*)d_ws;
  float* out = (float*)d_out;

  const int B = in_sizes[0] / NMAX;

  hipLaunchKernelGGL(precomp_kernel, dim3(65), dim3(256), 0, stream,
                     rod_id_embed, disk_W, disk_b, rod_W, rod_b, null_fourier, ws);
  hipLaunchKernelGGL(enc_kernel, dim3(B), dim3(256), 0, stream,
                     state, disk_W, rod_W, padding_embedding, ws, out);
}